// Round 11
// baseline (1329.216 us; speedup 1.0000x reference)
//
#include <hip/hip_runtime.h>
#include <hip/hip_cooperative_groups.h>

namespace cg = cooperative_groups;

typedef unsigned short ushort_t;
typedef unsigned int uint_t;

#define N_    384
#define E_    3072
#define CIN_  4096
#define EMB_  200
#define D_    512
#define NOBJ_ 151
#define NREL_ 51
#define K1_   (CIN_ + EMB_ + 128)   // 4424
#define K1P_  4448                  // pad to %32
#define K2_   (CIN_ + EMB_ + D_)    // 4808
#define K2P_  4832

__device__ __forceinline__ ushort_t f2b(float f) {
    uint_t u = __float_as_uint(f);
    u += 0x7FFFu + ((u >> 16) & 1u);           // RNE
    return (ushort_t)(u >> 16);
}

// ---------------- pair dedup ----------------
__global__ void k_pair_min(const int* __restrict__ rp, int* __restrict__ mapMin) {
    int e = blockIdx.x * blockDim.x + threadIdx.x;
    if (e >= E_) return;
    atomicMin(&mapMin[rp[2 * e] * N_ + rp[2 * e + 1]], e);
}
__global__ void k_pair_rep(const int* __restrict__ rp, const int* __restrict__ mapMin,
                           int* __restrict__ rep, int* __restrict__ deg_cnt) {
    int e = blockIdx.x * blockDim.x + threadIdx.x;
    if (e >= E_) return;
    int r = mapMin[rp[2 * e] * N_ + rp[2 * e + 1]];
    rep[e] = r;
    if (r == e) atomicAdd(&deg_cnt[rp[2 * e]], 1);
}
__global__ void k_inv_deg(const int* __restrict__ deg_cnt, float* __restrict__ inv_deg) {
    int i = blockIdx.x * blockDim.x + threadIdx.x;
    if (i < N_) inv_deg[i] = 1.0f / ((float)deg_cnt[i] + 1e-6f);
}

// ---------------- fused pos MLP + batchnorm (1 block) + pos2 ----------------
__global__ __launch_bounds__(1024) void k_pos_a(const float* __restrict__ pi,
                                                const float* __restrict__ w1,
                                                const float* __restrict__ b1,
                                                const float* __restrict__ g,
                                                const float* __restrict__ be,
                                                float* __restrict__ posn) {
    __shared__ float ph[N_ * 32];
    __shared__ float mu_s[32], rs_s[32];
    int tid = threadIdx.x;
    for (int idx = tid; idx < N_ * 32; idx += 1024) {
        int i = idx >> 5, f = idx & 31;
        float s = b1[f];
        for (int k = 0; k < 9; ++k) s += pi[i * 9 + k] * w1[f * 9 + k];
        ph[idx] = s;
    }
    __syncthreads();
    if (tid < 32) {
        float s = 0.f;
        for (int i = 0; i < N_; ++i) s += ph[i * 32 + tid];
        float m = s / N_;
        float v = 0.f;
        for (int i = 0; i < N_; ++i) { float d = ph[i * 32 + tid] - m; v += d * d; }
        mu_s[tid] = m;
        rs_s[tid] = rsqrtf(v / N_ + 1e-5f);
    }
    __syncthreads();
    for (int idx = tid; idx < N_ * 32; idx += 1024) {
        int f = idx & 31;
        posn[idx] = (ph[idx] - mu_s[f]) * rs_s[f] * g[f] + be[f];
    }
}
__global__ void k_pos2(const float* __restrict__ pn, const float* __restrict__ w,
                       const float* __restrict__ b, float* __restrict__ out) {
    int idx = blockIdx.x * blockDim.x + threadIdx.x;
    if (idx >= N_ * 128) return;
    int i = idx / 128, f = idx % 128;
    float s = b[f];
    for (int k = 0; k < 32; ++k) s += pn[i * 32 + k] * w[f * 32 + k];
    out[idx] = fmaxf(s, 0.f);
}

// ---------------- bf16 concat builders (zero-padded K) ----------------
__global__ void k_build_A1b(const float* __restrict__ x, const int* __restrict__ lab,
                            const float* __restrict__ emb1, const float* __restrict__ pe,
                            ushort_t* __restrict__ A) {
    int idx = blockIdx.x * blockDim.x + threadIdx.x;
    if (idx >= N_ * K1P_) return;
    int i = idx / K1P_, c = idx % K1P_;
    float v = 0.f;
    if (c < CIN_)             v = x[(size_t)i * CIN_ + c];
    else if (c < CIN_ + EMB_) v = emb1[lab[i] * EMB_ + (c - CIN_)];
    else if (c < K1_)         v = pe[i * 128 + (c - CIN_ - EMB_)];
    A[idx] = f2b(v);
}
__global__ void k_build_A2b(const float* __restrict__ x, const int* __restrict__ lab,
                            const float* __restrict__ emb2, const ushort_t* __restrict__ nsb,
                            ushort_t* __restrict__ A) {
    int idx = blockIdx.x * blockDim.x + threadIdx.x;
    if (idx >= N_ * K2P_) return;
    int i = idx / K2P_, c = idx % K2P_;
    ushort_t o = 0;
    if (c < CIN_)             o = f2b(x[(size_t)i * CIN_ + c]);
    else if (c < CIN_ + D_)   o = nsb[i * D_ + (c - CIN_)];
    else if (c < K2_)         o = f2b(emb2[lab[i] * EMB_ + (c - CIN_ - D_)]);
    A[idx] = o;
}
__global__ void k_build_ekb(const int* __restrict__ rp, const ushort_t* __restrict__ nsb,
                            ushort_t* __restrict__ ek) {
    int idx = blockIdx.x * blockDim.x + threadIdx.x;
    if (idx >= E_ * 2 * D_) return;
    int e = idx / (2 * D_), c = idx % (2 * D_);
    ek[idx] = (c < D_) ? nsb[rp[2 * e] * D_ + c] : nsb[rp[2 * e + 1] * D_ + (c - D_)];
}

// ---------------- f32 -> bf16 converts ----------------
// dedicated flat kernel for union_features (K=4096 pow2, pure streaming)
__global__ void k_conv_uf(const float* __restrict__ src, ushort_t* __restrict__ dst) {
    int i = blockIdx.x * blockDim.x + threadIdx.x;     // float4 index
    if (i >= E_ * CIN_ / 4) return;
    float4 v = ((const float4*)src)[i];
    uint2 o;
    o.x = (uint_t)f2b(v.x) | ((uint_t)f2b(v.y) << 16);
    o.y = (uint_t)f2b(v.z) | ((uint_t)f2b(v.w) << 16);
    ((uint2*)dst)[i] = o;
}
struct ConvDesc { const float* src; ushort_t* dst; int K, Kp, rows, rowsp; };
struct ConvArgs { ConvDesc d[14]; };
__global__ void k_conv_batch(ConvArgs a) {
    ConvDesc c = a.d[blockIdx.y];
    for (int row = blockIdx.x; row < c.rowsp; row += gridDim.x) {
        const float* src = c.src + (size_t)row * c.K;
        ushort_t* dst = c.dst + (size_t)row * c.Kp;
        bool inrow = row < c.rows;
        for (int k = threadIdx.x * 4; k < c.Kp; k += blockDim.x * 4) {
            uint2 ov = {0u, 0u};
            if (inrow && k < c.K) {
                float4 v = *(const float4*)(src + k);
                ov.x = (uint_t)f2b(v.x) | ((uint_t)f2b(v.y) << 16);
                ov.y = (uint_t)f2b(v.z) | ((uint_t)f2b(v.w) << 16);
            }
            *(uint2*)(dst + k) = ov;
        }
    }
}

// ---------------- scatter / pointwise (edge side) ----------------
__global__ void k_scatter_edge(const float* __restrict__ er, const int* __restrict__ rep,
                               float* __restrict__ es) {
    int e = blockIdx.x;
    int d = blockIdx.y * 256 + threadIdx.x;
    atomicAdd(&es[(size_t)rep[e] * D_ + d], er[(size_t)e * D_ + d]);
}
__global__ void k_broadcast_es(const int* __restrict__ rep, float* __restrict__ es,
                               ushort_t* __restrict__ esb) {
    int idx = blockIdx.x * blockDim.x + threadIdx.x;
    if (idx >= E_ * D_) return;
    int e = idx / D_, d = idx % D_;
    float v = es[(size_t)rep[e] * D_ + d];
    es[idx] = v;
    esb[idx] = f2b(v);
}
__global__ void k_epi(const float* __restrict__ raw, const float* __restrict__ bias,
                      float* __restrict__ fo, ushort_t* __restrict__ bo,
                      int total, int colmask, int relu) {
    int idx = blockIdx.x * blockDim.x + threadIdx.x;
    if (idx >= total) return;
    float v = raw[idx] + bias[idx & colmask];
    if (relu) v = fmaxf(v, 0.f);
    if (fo) fo[idx] = v;
    if (bo) bo[idx] = f2b(v);
}
__global__ void k_epi_rel(const float* __restrict__ raw, const float* __restrict__ relb,
                          float* __restrict__ out) {
    int idx = blockIdx.x * blockDim.x + threadIdx.x;
    if (idx >= E_ * NREL_) return;
    int row = idx / NREL_, col = idx % NREL_;
    out[idx] = raw[row * 64 + col] + relb[col];
}
__global__ void k_obj_dists(const int* __restrict__ lab, float* __restrict__ out) {
    int idx = blockIdx.x * blockDim.x + threadIdx.x;
    if (idx >= N_ * NOBJ_) return;
    out[idx] = (idx % NOBJ_ == lab[idx / NOBJ_]) ? 1000.f : -1000.f;
}

// ---------------- bf16 MFMA GEMM machinery ----------------
typedef __attribute__((ext_vector_type(8))) short sh8;
typedef __attribute__((ext_vector_type(4))) float f32x4;

#define GLOAD_LDS16(gp, lp)                                                        \
    __builtin_amdgcn_global_load_lds((__attribute__((address_space(1))) void*)(gp),\
                                     (__attribute__((address_space(3))) void*)(lp),\
                                     16, 0, 0)

// XCD-aware remap: groups all (x,z) blocks of one y-panel onto one XCD.
template <bool SWZ>
__device__ __forceinline__ void get_bxyz(int& bx, int& by, int& bz) {
    if (!SWZ) { bx = blockIdx.x; by = blockIdx.y; bz = blockIdx.z; return; }
    int nx = gridDim.x, nz = gridDim.z;
    int bid = blockIdx.x + nx * (blockIdx.y + gridDim.y * blockIdx.z);
    int r8 = bid & 7, i = bid >> 3;
    int per = nx * nz;
    int ygrp = i / per;
    int rem = i - ygrp * per;
    bx = rem % nx;
    bz = rem / nx;
    by = r8 + 8 * ygrp;
}

template <int FM, int FN>
__device__ __forceinline__ void gemm_kloop(ushort_t* As, ushort_t* Bs,
                                           const ushort_t* __restrict__ A,
                                           const ushort_t* __restrict__ B,
                                           f32x4 (&acc)[FM][FN],
                                           int K, int ks0, int ks1, int bm, int bn) {
    constexpr int BM = FM * 32, BN = FN * 32;
    constexpr int ATILES = (BM + 63) / 64, BTILES = (BN + 63) / 64;
    const int tid = threadIdx.x;
    const int lane = tid & 63, wid = tid >> 6;
    const int wr = wid >> 1, wc = wid & 1;
    const int ar = tid >> 2, ac = (tid & 3) * 8;
    const int l15 = lane & 15, lg = lane >> 4;
    for (int ks = ks0; ks < ks1; ++ks) {
        int k0 = ks * 32;
#pragma unroll
        for (int i = 0; i < ATILES; ++i) {
            int r = i * 64 + ar;
            if ((BM & 63) == 0 || r < BM)
                GLOAD_LDS16(A + (size_t)(bm + r) * K + k0 + ac, &As[r * 32 + ac]);
        }
#pragma unroll
        for (int i = 0; i < BTILES; ++i) {
            int r = i * 64 + ar;
            if ((BN & 63) == 0 || r < BN)
                GLOAD_LDS16(B + (size_t)(bn + r) * K + k0 + ac, &Bs[r * 32 + ac]);
        }
        __syncthreads();
        sh8 af[FM], bf[FN];
#pragma unroll
        for (int m = 0; m < FM; ++m)
            af[m] = *(const sh8*)&As[(wr * FM * 16 + m * 16 + l15) * 32 + lg * 8];
#pragma unroll
        for (int n = 0; n < FN; ++n)
            bf[n] = *(const sh8*)&Bs[(wc * FN * 16 + n * 16 + l15) * 32 + lg * 8];
#pragma unroll
        for (int m = 0; m < FM; ++m)
#pragma unroll
            for (int n = 0; n < FN; ++n)
                acc[m][n] = __builtin_amdgcn_mfma_f32_16x16x32_bf16(af[m], bf[n], acc[m][n], 0, 0, 0);
        __syncthreads();
    }
}

template <int FM, int FN, bool SWZ = false>
__global__ __launch_bounds__(256) void gemm_mfma(const ushort_t* __restrict__ A,
                                                 const ushort_t* __restrict__ B,
                                                 const float* __restrict__ bias,
                                                 float* __restrict__ C,
                                                 ushort_t* __restrict__ Cb,
                                                 int M, int N, int K, int relu) {
    __shared__ ushort_t As[FM * 32 * 32];
    __shared__ ushort_t Bs[FN * 32 * 32];
    int bx, by, bz;
    get_bxyz<SWZ>(bx, by, bz);
    const int bm = by * FM * 32, bn = bx * FN * 32;
    f32x4 acc[FM][FN];
#pragma unroll
    for (int m = 0; m < FM; ++m)
#pragma unroll
        for (int n = 0; n < FN; ++n) acc[m][n] = (f32x4){0.f, 0.f, 0.f, 0.f};
    gemm_kloop<FM, FN>(As, Bs, A, B, acc, K, 0, K / 32, bm, bn);
    const int lane = threadIdx.x & 63, wid = threadIdx.x >> 6;
    const int l15 = lane & 15, lg = lane >> 4;
    const int r0 = bm + (wid >> 1) * FM * 16, c0 = bn + (wid & 1) * FN * 16;
#pragma unroll
    for (int m = 0; m < FM; ++m)
#pragma unroll
        for (int n = 0; n < FN; ++n)
#pragma unroll
            for (int j = 0; j < 4; ++j) {
                int row = r0 + m * 16 + lg * 4 + j;
                int col = c0 + n * 16 + l15;
                if (row < M && col < N) {
                    float v = acc[m][n][j] + (bias ? bias[col] : 0.f);
                    if (relu) v = fmaxf(v, 0.f);
                    if (C)  C[(size_t)row * N + col] = v;
                    if (Cb) Cb[(size_t)row * N + col] = f2b(v);
                }
            }
}

// split-K via f32 atomicAdd into pre-zeroed C
template <int FM, int FN, bool SWZ = false>
__global__ __launch_bounds__(256) void gemm_splitk(const ushort_t* __restrict__ A,
                                                   const ushort_t* __restrict__ B,
                                                   float* __restrict__ C,
                                                   int M, int N, int K, int S) {
    __shared__ ushort_t As[FM * 32 * 32];
    __shared__ ushort_t Bs[FN * 32 * 32];
    int bx, by, bz;
    get_bxyz<SWZ>(bx, by, bz);
    const int nsteps = K / 32;
    const int ss = (nsteps + S - 1) / S;
    const int ks0 = bz * ss;
    const int ks1 = min(nsteps, ks0 + ss);
    if (ks0 >= ks1) return;
    const int bm = by * FM * 32, bn = bx * FN * 32;
    f32x4 acc[FM][FN];
#pragma unroll
    for (int m = 0; m < FM; ++m)
#pragma unroll
        for (int n = 0; n < FN; ++n) acc[m][n] = (f32x4){0.f, 0.f, 0.f, 0.f};
    gemm_kloop<FM, FN>(As, Bs, A, B, acc, K, ks0, ks1, bm, bn);
    const int lane = threadIdx.x & 63, wid = threadIdx.x >> 6;
    const int l15 = lane & 15, lg = lane >> 4;
    const int r0 = bm + (wid >> 1) * FM * 16, c0 = bn + (wid & 1) * FN * 16;
#pragma unroll
    for (int m = 0; m < FM; ++m)
#pragma unroll
        for (int n = 0; n < FN; ++n)
#pragma unroll
            for (int j = 0; j < 4; ++j) {
                int row = r0 + m * 16 + lg * 4 + j;
                int col = c0 + n * 16 + l15;
                if (row < M && col < N)
                    atomicAdd(&C[(size_t)row * N + col], acc[m][n][j]);
            }
}

// ---------------- fused ghe-GEMM + edge GRU ----------------
__global__ __launch_bounds__(256) void k_ghe_gru(const ushort_t* __restrict__ esb_in,
                                                 const ushort_t* __restrict__ W,
                                                 const float* __restrict__ gi,
                                                 const float* __restrict__ es_in,
                                                 float* __restrict__ es_out,
                                                 ushort_t* __restrict__ esb_out) {
    __shared__ ushort_t As[64 * 32];
    __shared__ ushort_t Bs[96 * 32];
    int bid = blockIdx.x + gridDim.x * blockIdx.y;
    int r8 = bid & 7, i = bid >> 3;
    int per = gridDim.x;
    int ygrp = i / per;
    int x = i - ygrp * per;
    int y = r8 + 8 * ygrp;
    const int bm = y * 64;
    const int dcol0 = x * 32;
    const int tid = threadIdx.x;
    const int lane = tid & 63, wid = tid >> 6;
    const int wr = wid >> 1, wc = wid & 1;
    const int ar = tid >> 2, ac = (tid & 3) * 8;
    const int l15 = lane & 15, lg = lane >> 4;
    f32x4 acc[2][3];
#pragma unroll
    for (int m = 0; m < 2; ++m)
#pragma unroll
        for (int g = 0; g < 3; ++g) acc[m][g] = (f32x4){0.f, 0.f, 0.f, 0.f};

    for (int k0 = 0; k0 < D_; k0 += 32) {
        GLOAD_LDS16(esb_in + (size_t)(bm + ar) * D_ + k0 + ac, &As[ar * 32 + ac]);
        {
            int rr = ar;
            int wrow = (rr >> 5) * D_ + dcol0 + (rr & 31);
            GLOAD_LDS16(W + (size_t)wrow * D_ + k0 + ac, &Bs[rr * 32 + ac]);
        }
        if (tid < 128) {
            int rr = 64 + ar;
            int wrow = 2 * D_ + dcol0 + (rr & 31);
            GLOAD_LDS16(W + (size_t)wrow * D_ + k0 + ac, &Bs[rr * 32 + ac]);
        }
        __syncthreads();
        sh8 af[2], bf[3];
#pragma unroll
        for (int m = 0; m < 2; ++m)
            af[m] = *(const sh8*)&As[(wr * 32 + m * 16 + l15) * 32 + lg * 8];
#pragma unroll
        for (int g = 0; g < 3; ++g)
            bf[g] = *(const sh8*)&Bs[(g * 32 + wc * 16 + l15) * 32 + lg * 8];
#pragma unroll
        for (int m = 0; m < 2; ++m)
#pragma unroll
            for (int g = 0; g < 3; ++g)
                acc[m][g] = __builtin_amdgcn_mfma_f32_16x16x32_bf16(af[m], bf[g], acc[m][g], 0, 0, 0);
        __syncthreads();
    }

    const int d = dcol0 + wc * 16 + l15;
#pragma unroll
    for (int m = 0; m < 2; ++m)
#pragma unroll
        for (int j = 0; j < 4; ++j) {
            int row = bm + wr * 32 + m * 16 + lg * 4 + j;
            size_t gbase = (size_t)row * 1536 + d;
            float r = 1.f / (1.f + expf(-(gi[gbase] + acc[m][0][j])));
            float z = 1.f / (1.f + expf(-(gi[gbase + 512] + acc[m][1][j])));
            float g = tanhf(gi[gbase + 1024] + r * acc[m][2][j]);
            float hv = es_in[(size_t)row * D_ + d];
            float nv = (1.f - z) * g + z * hv;
            es_out[(size_t)row * D_ + d] = nv;
            esb_out[(size_t)row * D_ + d] = f2b(nv);
        }
}

// ---------------- cooperative node-side mega-kernel ----------------
// Phases (grid.sync between): zero | scatter_e2n | f2b | e2n-MLP(w1,w2) |
// 3x { scatter_n2n | scale+rezero | w1 | w2+combine | gin/ghn | GRU }
struct NodeArgs {
    const int* rp; const int* rep; const float* inv_deg;
    const float* es;
    float* e2n; ushort_t* e2nb; float* e2nm;
    const ushort_t* e2nw1b; const float* e2nb1;
    const ushort_t* e2nw2b; const float* e2nb2;
    const ushort_t* n2nw1b; const float* n2nb1;
    const ushort_t* n2nw2b; const float* n2nb2;
    const ushort_t* ngwihb; const ushort_t* ngwhhb;
    const float* ngbih; const float* ngbhh;
    float* n2n; ushort_t* n2nbuf; ushort_t* tmpb; ushort_t* xinb;
    float* gin; float* ghn;
    float* ns; ushort_t* nsb;
};

// GEMM phase helper: M=384 rows, Nn cols, K=512; FM=1 tiles; grid-stride tiles.
// MODE 0: relu(acc+bias)->bf16   1: relu(acc+bias)->f32
// MODE 2: f2b(0.5*relu(acc+bias)+0.5*aux)->bf16   3: acc->f32
template <int FN, int MODE>
__device__ __forceinline__ void coop_gemm(ushort_t* As, ushort_t* Bs,
                                          const ushort_t* __restrict__ A,
                                          const ushort_t* __restrict__ B,
                                          int Nn,
                                          const float* __restrict__ bias,
                                          const float* __restrict__ aux,
                                          float* __restrict__ fo,
                                          ushort_t* __restrict__ bo) {
    const int tN = Nn / (FN * 32);
    const int ntiles = (N_ / 32) * tN;
    const int lane = threadIdx.x & 63, wid = threadIdx.x >> 6;
    const int l15 = lane & 15, lg = lane >> 4;
    for (int t = blockIdx.x; t < ntiles; t += gridDim.x) {
        int by = t / tN, bx = t - by * tN;
        int bm = by * 32, bn = bx * FN * 32;
        f32x4 acc[1][FN];
#pragma unroll
        for (int n = 0; n < FN; ++n) acc[0][n] = (f32x4){0.f, 0.f, 0.f, 0.f};
        gemm_kloop<1, FN>(As, Bs, A, B, acc, D_, 0, D_ / 32, bm, bn);
        const int r0 = bm + (wid >> 1) * 16, c0 = bn + (wid & 1) * FN * 16;
#pragma unroll
        for (int n = 0; n < FN; ++n)
#pragma unroll
            for (int j = 0; j < 4; ++j) {
                int row = r0 + lg * 4 + j;
                int col = c0 + n * 16 + l15;
                size_t idx = (size_t)row * Nn + col;
                float v = acc[0][n][j];
                if (MODE == 0) { v = fmaxf(v + bias[col], 0.f); bo[idx] = f2b(v); }
                if (MODE == 1) { v = fmaxf(v + bias[col], 0.f); fo[idx] = v; }
                if (MODE == 2) { v = fmaxf(v + bias[col], 0.f); bo[idx] = f2b(0.5f * v + 0.5f * aux[idx]); }
                if (MODE == 3) { fo[idx] = v; }
            }
    }
}

__global__ __launch_bounds__(256) void k_node_all(NodeArgs a) {
    cg::grid_group grid = cg::this_grid();
    __shared__ ushort_t As[32 * 32];
    __shared__ ushort_t Bs[256 * 32];
    const int gsz = gridDim.x * blockDim.x;
    const int gid = blockIdx.x * blockDim.x + threadIdx.x;

    // P0: zero e2n + n2n
    for (int i = gid; i < N_ * D_; i += gsz) { a.e2n[i] = 0.f; a.n2n[i] = 0.f; }
    grid.sync();
    // P1: scatter_e2n
    for (int i = gid; i < E_ * D_; i += gsz) {
        int e = i >> 9, d = i & 511;
        if (a.rep[e] == e) atomicAdd(&a.e2n[a.rp[2 * e + 1] * D_ + d], a.es[(size_t)e * D_ + d]);
    }
    grid.sync();
    // P2: f2b e2n
    for (int i = gid; i < N_ * D_; i += gsz) a.e2nb[i] = f2b(a.e2n[i]);
    grid.sync();
    // P3: e2n w1 (relu) -> tmpb
    coop_gemm<2, 0>(As, Bs, a.e2nb, a.e2nw1b, D_, a.e2nb1, nullptr, nullptr, a.tmpb);
    grid.sync();
    // P4: e2n w2 (relu) -> e2nm f32
    coop_gemm<2, 1>(As, Bs, a.tmpb, a.e2nw2b, D_, a.e2nb2, nullptr, a.e2nm, nullptr);
    grid.sync();

    for (int it = 0; it < 3; ++it) {
        // A: scatter_n2n (n2n pre-zeroed)
        for (int i = gid; i < E_ * D_; i += gsz) {
            int e = i >> 9, d = i & 511;
            if (a.rep[e] == e) atomicAdd(&a.n2n[a.rp[2 * e] * D_ + d], a.ns[a.rp[2 * e + 1] * D_ + d]);
        }
        grid.sync();
        // B: scale -> n2nbuf bf16, and re-zero n2n for next iteration
        for (int i = gid; i < N_ * D_; i += gsz) {
            a.n2nbuf[i] = f2b(a.n2n[i] * a.inv_deg[i >> 9]);
            a.n2n[i] = 0.f;
        }
        grid.sync();
        // C: n2n w1 (relu) -> tmpb
        coop_gemm<2, 0>(As, Bs, a.n2nbuf, a.n2nw1b, D_, a.n2nb1, nullptr, nullptr, a.tmpb);
        grid.sync();
        // D: n2n w2 (relu) + combine with e2nm -> xinb
        coop_gemm<2, 2>(As, Bs, a.tmpb, a.n2nw2b, D_, a.n2nb2, a.e2nm, nullptr, a.xinb);
        grid.sync();
        // E: gin = xinb@ngwih, ghn = nsb@ngwhh (independent, no sync between)
        coop_gemm<8, 3>(As, Bs, a.xinb, a.ngwihb, 3 * D_, nullptr, nullptr, a.gin, nullptr);
        coop_gemm<8, 3>(As, Bs, a.nsb, a.ngwhhb, 3 * D_, nullptr, nullptr, a.ghn, nullptr);
        grid.sync();
        // F: GRU pointwise -> ns, nsb
        for (int i = gid; i < N_ * D_; i += gsz) {
            int d = i & 511;
            size_t b3 = (size_t)(i >> 9) * 1536;
            float ir = a.gin[b3 + d] + a.ngbih[d];
            float iz = a.gin[b3 + 512 + d] + a.ngbih[512 + d];
            float ig = a.gin[b3 + 1024 + d] + a.ngbih[1024 + d];
            float hr = a.ghn[b3 + d] + a.ngbhh[d];
            float hz = a.ghn[b3 + 512 + d] + a.ngbhh[512 + d];
            float hg = a.ghn[b3 + 1024 + d] + a.ngbhh[1024 + d];
            float r = 1.f / (1.f + expf(-(ir + hr)));
            float z = 1.f / (1.f + expf(-(iz + hz)));
            float g = tanhf(ig + r * hg);
            float nv = (1.f - z) * g + z * a.ns[i];
            a.ns[i] = nv;
            a.nsb[i] = f2b(nv);
        }
        grid.sync();
    }
}

static inline dim3 mgrid(int M, int N, int FM, int FN) {
    return dim3((N + FN * 32 - 1) / (FN * 32), (M + FM * 32 - 1) / (FM * 32));
}
static inline dim3 sgrid(int M, int N, int FM, int FN, int S) {
    dim3 g = mgrid(M, N, FM, FN);
    return dim3(g.x, g.y, S);
}

extern "C" void kernel_launch(void* const* d_in, const int* in_sizes, int n_in,
                              void* d_out, int out_size, void* d_ws, size_t ws_size,
                              hipStream_t stream) {
    const float* x      = (const float*)d_in[0];
    const float* posi   = (const float*)d_in[1];
    const float* unionf = (const float*)d_in[2];
    const int*   lab    = (const int*)d_in[3];
    const int*   rp     = (const int*)d_in[4];
    const float* emb1   = (const float*)d_in[5];
    const float* emb2   = (const float*)d_in[6];
    const float* nw     = (const float*)d_in[7];
    const float* nb     = (const float*)d_in[8];
    const float* nw2    = (const float*)d_in[9];
    const float* nb2    = (const float*)d_in[10];
    const float* ew     = (const float*)d_in[11];
    const float* eb     = (const float*)d_in[12];
    const float* pw1    = (const float*)d_in[13];
    const float* pb1    = (const float*)d_in[14];
    const float* pg     = (const float*)d_in[15];
    const float* pbe    = (const float*)d_in[16];
    const float* pw2    = (const float*)d_in[17];
    const float* pb2    = (const float*)d_in[18];
    const float* ngwih  = (const float*)d_in[19];
    const float* ngwhh  = (const float*)d_in[20];
    const float* ngbih  = (const float*)d_in[21];
    const float* ngbhh  = (const float*)d_in[22];
    const float* egwih  = (const float*)d_in[23];
    const float* egwhh  = (const float*)d_in[24];
    const float* n2nw1  = (const float*)d_in[25];
    const float* n2nb1  = (const float*)d_in[26];
    const float* n2nw2  = (const float*)d_in[27];
    const float* n2nb2  = (const float*)d_in[28];
    const float* e2nw1  = (const float*)d_in[29];
    const float* e2nb1  = (const float*)d_in[30];
    const float* e2nw2  = (const float*)d_in[31];
    const float* e2nb2  = (const float*)d_in[32];
    const float* n2ew1  = (const float*)d_in[33];
    const float* n2eb1  = (const float*)d_in[34];
    const float* n2ew2  = (const float*)d_in[35];
    const float* n2eb2  = (const float*)d_in[36];
    const float* relw   = (const float*)d_in[37];
    const float* relb   = (const float*)d_in[38];

    size_t off = 0;
    auto alloc = [&](size_t bytes) {
        off = (off + 255) & ~(size_t)255;
        char* p = (char*)d_ws + off;
        off += bytes;
        return (void*)p;
    };
    int*      mapMin  = (int*)alloc((size_t)N_ * N_ * 4);
    int*      rep     = (int*)alloc(E_ * 4);
    int*      deg_cnt = (int*)alloc(N_ * 4);
    float*    inv_deg = (float*)alloc(N_ * 4);
    float*    posn    = (float*)alloc(N_ * 32 * 4);
    float*    pe      = (float*)alloc(N_ * 128 * 4);
    float*    ns      = (float*)alloc((size_t)N_ * D_ * 4);
    ushort_t* nsb     = (ushort_t*)alloc((size_t)N_ * D_ * 2);
    float*    nsraw   = (float*)alloc((size_t)N_ * D_ * 4);
    float*    n2n     = (float*)alloc((size_t)N_ * D_ * 4);
    float*    gin     = (float*)alloc((size_t)N_ * 3 * D_ * 4);
    float*    ghn     = (float*)alloc((size_t)N_ * 3 * D_ * 4);
    float*    e2nm    = (float*)alloc((size_t)N_ * D_ * 4);
    float*    relraw  = (float*)alloc((size_t)E_ * 64 * 4);
    // union: A1b / A2b / ekb -- sequential lifetimes
    char*     unionU  = (char*)alloc((size_t)E_ * 2 * D_ * 2);
    ushort_t* A1b = (ushort_t*)unionU;
    ushort_t* A2b = (ushort_t*)unionU;
    ushort_t* ekb = (ushort_t*)unionU;
    // union: ufb bf16 (early) / gie f32 (late)
    char*     ufbU = (char*)alloc((size_t)E_ * CIN_ * 2);
    ushort_t* ufb = (ushort_t*)ufbU;
    float*    gie = (float*)ufbU;
    // union: erep f32 (early) / erepb+msgb bf16 (late)
    char*     erepU = (char*)alloc((size_t)E_ * D_ * 4);
    float*    erep  = (float*)erepU;
    ushort_t* erepb = (ushort_t*)erepU;
    ushort_t* msgb  = (ushort_t*)(erepU + (size_t)E_ * D_ * 2);
    float*    es    = (float*)alloc((size_t)E_ * D_ * 4);
    ushort_t* esb   = (ushort_t*)alloc((size_t)E_ * D_ * 2);
    float*    es2   = (float*)alloc((size_t)E_ * D_ * 4);
    ushort_t* esb2  = (ushort_t*)alloc((size_t)E_ * D_ * 2);
    float*    e2n   = (float*)alloc((size_t)N_ * D_ * 4);
    ushort_t* e2nb  = (ushort_t*)alloc((size_t)N_ * D_ * 2);
    ushort_t* tmpb  = (ushort_t*)alloc((size_t)N_ * D_ * 2);
    ushort_t* n2nb  = (ushort_t*)alloc((size_t)N_ * D_ * 2);
    ushort_t* xinb  = (ushort_t*)alloc((size_t)N_ * D_ * 2);
    // bf16 weights
    ushort_t* nwb     = (ushort_t*)alloc((size_t)D_ * K1P_ * 2);
    ushort_t* nw2b    = (ushort_t*)alloc((size_t)D_ * K2P_ * 2);
    ushort_t* ewb     = (ushort_t*)alloc((size_t)D_ * CIN_ * 2);
    ushort_t* ngwihb  = (ushort_t*)alloc((size_t)3 * D_ * D_ * 2);
    ushort_t* ngwhhb  = (ushort_t*)alloc((size_t)3 * D_ * D_ * 2);
    ushort_t* egwihb  = (ushort_t*)alloc((size_t)3 * D_ * D_ * 2);
    ushort_t* egwhhb  = (ushort_t*)alloc((size_t)3 * D_ * D_ * 2);
    ushort_t* n2nw1b  = (ushort_t*)alloc((size_t)D_ * D_ * 2);
    ushort_t* n2nw2b  = (ushort_t*)alloc((size_t)D_ * D_ * 2);
    ushort_t* e2nw1b  = (ushort_t*)alloc((size_t)D_ * D_ * 2);
    ushort_t* e2nw2b  = (ushort_t*)alloc((size_t)D_ * D_ * 2);
    ushort_t* n2ew1b  = (ushort_t*)alloc((size_t)D_ * 2 * D_ * 2);
    ushort_t* n2ew2b  = (ushort_t*)alloc((size_t)D_ * D_ * 2);
    ushort_t* relwb   = (ushort_t*)alloc((size_t)64 * D_ * 2);
    if (off > ws_size) return;

    float* out_obj = (float*)d_out;
    float* out_rel = (float*)d_out + N_ * NOBJ_;

    // ---- conversions: unionf flat kernel + weights batch ----
    k_conv_uf<<<(E_ * CIN_ / 4 + 255) / 256, 256, 0, stream>>>(unionf, ufb);
    ConvArgs ca;
    int ci = 0;
    auto addc = [&](const float* s, ushort_t* dptr, int K, int Kp, int rows, int rowsp) {
        ca.d[ci++] = ConvDesc{s, dptr, K, Kp, rows, rowsp};
    };
    addc(nw,    nwb,    K1_,      K1P_,     D_,       D_);
    addc(nw2,   nw2b,   K2_,      K2P_,     D_,       D_);
    addc(ew,    ewb,    CIN_,     CIN_,     D_,       D_);
    addc(ngwih, ngwihb, D_,       D_,       3 * D_,   3 * D_);
    addc(ngwhh, ngwhhb, D_,       D_,       3 * D_,   3 * D_);
    addc(egwih, egwihb, D_,       D_,       3 * D_,   3 * D_);
    addc(egwhh, egwhhb, D_,       D_,       3 * D_,   3 * D_);
    addc(n2nw1, n2nw1b, D_,       D_,       D_,       D_);
    addc(n2nw2, n2nw2b, D_,       D_,       D_,       D_);
    addc(e2nw1, e2nw1b, D_,       D_,       D_,       D_);
    addc(e2nw2, e2nw2b, D_,       D_,       D_,       D_);
    addc(n2ew1, n2ew1b, 2 * D_,   2 * D_,   D_,       D_);
    addc(n2ew2, n2ew2b, D_,       D_,       D_,       D_);
    addc(relw,  relwb,  D_,       D_,       NREL_,    64);
    k_conv_batch<<<dim3(512, 14), 256, 0, stream>>>(ca);

    // ---- pair dedup + degrees ----
    (void)hipMemsetAsync(mapMin, 0x7F, (size_t)N_ * N_ * 4, stream);
    (void)hipMemsetAsync(deg_cnt, 0, N_ * 4, stream);
    k_pair_min<<<(E_ + 255) / 256, 256, 0, stream>>>(rp, mapMin);
    k_pair_rep<<<(E_ + 255) / 256, 256, 0, stream>>>(rp, mapMin, rep, deg_cnt);
    k_inv_deg<<<(N_ + 255) / 256, 256, 0, stream>>>(deg_cnt, inv_deg);

    // ---- pos embed ----
    k_pos_a<<<1, 1024, 0, stream>>>(posi, pw1, pb1, pg, pbe, posn);
    k_pos2<<<(N_ * 128 + 255) / 256, 256, 0, stream>>>(posn, pw2, pb2, pe);

    // ---- node_states = [x|emb1|pos] @ nw^T + nb (split-K S=8) ----
    k_build_A1b<<<((size_t)N_ * K1P_ + 255) / 256, 256, 0, stream>>>(x, lab, emb1, pe, A1b);
    (void)hipMemsetAsync(nsraw, 0, (size_t)N_ * D_ * 4, stream);
    gemm_splitk<1, 1><<<sgrid(N_, D_, 1, 1, 8), 256, 0, stream>>>(A1b, nwb, nsraw, N_, D_, K1P_, 8);
    k_epi<<<(N_ * D_ + 255) / 256, 256, 0, stream>>>(nsraw, nb, ns, nsb, N_ * D_, D_ - 1, 0);

    // ---- edge_rep (split-K S=4 + XCD swizzle) + sparse edge_states ----
    (void)hipMemsetAsync(erep, 0, (size_t)E_ * D_ * 4, stream);
    gemm_splitk<2, 2, true><<<sgrid(E_, D_, 2, 2, 4), 256, 0, stream>>>(ufb, ewb, erep, E_, D_, CIN_, 4);
    k_epi<<<((size_t)E_ * D_ + 255) / 256, 256, 0, stream>>>(erep, eb, erep, nullptr, E_ * D_, D_ - 1, 0);
    (void)hipMemsetAsync(es, 0, (size_t)E_ * D_ * 4, stream);
    k_scatter_edge<<<dim3(E_, 2), 256, 0, stream>>>(erep, rep, es);
    k_broadcast_es<<<(E_ * D_ + 255) / 256, 256, 0, stream>>>(rep, es, esb);

    // ---- cooperative node-side mega-kernel ----
    {
        NodeArgs na;
        na.rp = rp; na.rep = rep; na.inv_deg = inv_deg; na.es = es;
        na.e2n = e2n; na.e2nb = e2nb; na.e2nm = e2nm;
        na.e2nw1b = e2nw1b; na.e2nb1 = e2nb1;
        na.e2nw2b = e2nw2b; na.e2nb2 = e2nb2;
        na.n2nw1b = n2nw1b; na.n2nb1 = n2nb1;
        na.n2nw2b = n2nw2b; na.n2nb2 = n2nb2;
        na.ngwihb = ngwihb; na.ngwhhb = ngwhhb;
        na.ngbih = ngbih; na.ngbhh = ngbhh;
        na.n2n = n2n; na.n2nbuf = n2nb; na.tmpb = tmpb; na.xinb = xinb;
        na.gin = gin; na.ghn = ghn;
        na.ns = ns; na.nsb = nsb;
        void* kargs[] = { &na };
        (void)hipLaunchCooperativeKernel((const void*)k_node_all, dim3(256), dim3(256),
                                         kargs, 0, stream);
    }

    // ---- obj_dists ----
    k_obj_dists<<<(N_ * NOBJ_ + 255) / 256, 256, 0, stream>>>(lab, out_obj);

    // ---- node_states2 (split-K S=8) ----
    k_build_A2b<<<((size_t)N_ * K2P_ + 255) / 256, 256, 0, stream>>>(x, lab, emb2, nsb, A2b);
    (void)hipMemsetAsync(nsraw, 0, (size_t)N_ * D_ * 4, stream);
    gemm_splitk<1, 1><<<sgrid(N_, D_, 1, 1, 8), 256, 0, stream>>>(A2b, nw2b, nsraw, N_, D_, K2P_, 8);
    k_epi<<<(N_ * D_ + 255) / 256, 256, 0, stream>>>(nsraw, nb2, ns, nsb, N_ * D_, D_ - 1, 0);

    // ---- edge loop: msg + gi loop-invariant; GRU fused into ghe GEMM ----
    k_build_ekb<<<((size_t)E_ * 2 * D_ + 255) / 256, 256, 0, stream>>>(rp, nsb, ekb);
    gemm_mfma<2, 2, true><<<mgrid(E_, D_, 2, 2), 256, 0, stream>>>(ekb, n2ew1b, n2eb1, nullptr, erepb, E_, D_, 2 * D_, 1);
    gemm_mfma<2, 2, true><<<mgrid(E_, D_, 2, 2), 256, 0, stream>>>(erepb, n2ew2b, n2eb2, nullptr, msgb, E_, D_, D_, 1);
    gemm_mfma<2, 4, true><<<mgrid(E_, 3 * D_, 2, 4), 256, 0, stream>>>(msgb, egwihb, nullptr, gie, nullptr, E_, 3 * D_, D_, 0);
    {
        float* esI = es;  ushort_t* esbI = esb;
        float* esO = es2; ushort_t* esbO = esb2;
        for (int it = 0; it < 3; ++it) {
            k_ghe_gru<<<dim3(16, 48), 256, 0, stream>>>(esbI, egwhhb, gie, esI, esO, esbO);
            float* tf = esI; esI = esO; esO = tf;
            ushort_t* tb = esbI; esbI = esbO; esbO = tb;
        }
        (void)hipMemsetAsync(relraw, 0, (size_t)E_ * 64 * 4, stream);
        gemm_splitk<1, 1><<<sgrid(E_, 64, 1, 1, 4), 256, 0, stream>>>(esbI, relwb, relraw, E_, 64, D_, 4);
        k_epi_rel<<<(E_ * NREL_ + 255) / 256, 256, 0, stream>>>(relraw, relb, out_rel);
    }
}